// Round 17
// baseline (426.262 us; speedup 1.0000x reference)
//
#include <hip/hip_runtime.h>

#define FCOUNT 786432   // 12 * 256 * 256
#define SEGBITS 13
#define SEG 8192        // facets per segment (passC LDS geometry)
#define NSEG 96         // FCOUNT / SEG
#define JBITS 18
#define JMASK ((1 << JBITS) - 1)
#define BLK 256
#define ITEMS_A 8
#define CHUNKA (BLK * ITEMS_A)  // 2048 items per A-chunk
#define ITEMS_B 4
#define CHUNKB (BLK * ITEMS_B)  // 1024 items per B-chunk (proven r12/r15 geometry)
#define JPT 16                  // j's per thread in passD (4 q-groups of 4)
#define CAPA 2400       // idx1-seg bucket cap (mean 2083, sigma 45)
#define CAPB 2048       // c-seg bucket cap (mean ~1667, sigma 41)
#define EPT_A 10        // ceil(CAPA / BLK)
#define EPT_B 8         // CAPB / BLK
#define PSTRIDE_A (NSEG * CAPA)
#define PSTRIDE_B (NSEG * CAPB)

typedef int   iv4 __attribute__((ext_vector_type(4)));
typedef float fv4 __attribute__((ext_vector_type(4)));

template <int NS> struct MsCtl {
    int hist[NS], lstart[NS], gbase[NS], cursor[NS], wsum[BLK / 64];
    int total;
};

template <int NS>
__device__ __forceinline__ void ms_zero(MsCtl<NS>& C, int tid) {
    if (tid < NS) { C.hist[tid] = 0; C.cursor[tid] = 0; }
}

// hist complete: exclusive scan -> lstart, global bucket alloc -> gbase, total
template <int NS>
__device__ __forceinline__ void ms_scan_alloc(MsCtl<NS>& C, int* __restrict__ cntRow,
                                              int tid) {
    int v = (tid < NS) ? C.hist[tid] : 0;
    int lane = tid & 63, w = tid >> 6;
    #pragma unroll
    for (int d = 1; d < 64; d <<= 1) {
        int u = __shfl_up(v, d, 64);
        if (lane >= d) v += u;
    }
    if (lane == 63) C.wsum[w] = v;
    __syncthreads();
    int add = 0;
    for (int ww = 0; ww < w; ww++) add += C.wsum[ww];
    v += add;
    if (tid < NS) {
        C.lstart[tid] = v - C.hist[tid];
        C.gbase[tid] = C.hist[tid] ? atomicAdd(&cntRow[tid], C.hist[tid]) : 0;
        if (tid == NS - 1) C.total = v;
    }
}

// DENSE staged copy; bucket writes CACHED (sub-line scatter runs merge in L2
// -- NT here caused 2.6x HBM write amplification, round 14 lesson).
// loc lands in the block's LDS window (flushed coalesced NT later).
template <int NS>
__device__ __forceinline__ void ms_copy_lds(const MsCtl<NS>& C,
                                            const int* __restrict__ staged,
                                            const unsigned char* __restrict__ stagedSeg,
                                            int* __restrict__ bktPair, int cap,
                                            int* __restrict__ locStage, int jb,
                                            int tid) {
    int total = C.total;
    for (int i = tid; i < total; i += BLK) {
        int s = stagedSeg[i];
        int d = C.gbase[s] + (i - C.lstart[s]);
        if (d < cap) {
            int e = staged[i];
            int slot = s * cap + d;
            bktPair[slot] = e;
            locStage[(e & JMASK) - jb] = slot;
        }
    }
}

// ---------------------------------------------------------------------------
// Fused binning kernel (r15 structure). Per pair: nchunkB B-chunks (corr
// gather + c-seg multisplit) and nchunkA A-chunks (idx1 f-seg multisplit),
// interleaved 2:1. Corr gathers are NON-TEMPORAL (no L1 allocation): the
// B path is bound by L1 outstanding-miss capacity x L2 latency; corr has
// ~1.3x L1 reuse only, so bypassing L1 frees the miss path.
__global__ __launch_bounds__(BLK) void bin_fused_kernel(
        const int* __restrict__ corr, const int* __restrict__ idx0,
        const int* __restrict__ idx1, int* __restrict__ cntA,
        int* __restrict__ cntB, int* __restrict__ bktA, int* __restrict__ bktB,
        int* __restrict__ locA, int* __restrict__ locB,
        int N, int nchunkB, int nchunkA, int b0) {
    __shared__ MsCtl<NSEG> C;
    __shared__ int staged[CHUNKA];              // B path uses first CHUNKB
    __shared__ unsigned char stagedSeg[CHUNKA];
    __shared__ int locStage[CHUNKA];
    int id = blockIdx.x, xcd = id & 7, k = id >> 3;   // XCD-pin pair
    int per = nchunkB + nchunkA;
    int bl = xcd + 8 * (k / per), m = k % per;
    int b = b0 + bl, tid = threadIdx.x;
    bool isA; int ci;
    if (nchunkB == 2 * nchunkA) {               // interleave B,B,A,B,B,A,...
        isA = (m % 3 == 2);
        ci = isA ? m / 3 : m - (m + 1) / 3;
    } else {
        isA = (m >= nchunkB);
        ci = isA ? m - nchunkB : m;
    }

    if (isA) {
        // ---------------- binA path (idx1 multisplit) ----------------
        int jb = ci * CHUNKA;
        const int* row = idx1 + (size_t)b * N;
        int f[ITEMS_A];
        #pragma unroll
        for (int q = 0; q < ITEMS_A / 4; q++) {
            int j0 = jb + q * (BLK * 4) + tid * 4;
            if (j0 + 3 < N) {
                iv4 v = __builtin_nontemporal_load((const iv4*)(row + j0));
                f[q * 4 + 0] = v[0]; f[q * 4 + 1] = v[1];
                f[q * 4 + 2] = v[2]; f[q * 4 + 3] = v[3];
            } else {
                #pragma unroll
                for (int s = 0; s < 4; s++)
                    f[q * 4 + s] = (j0 + s < N) ? row[j0 + s] : -1;
            }
        }
        for (int t = tid; t < CHUNKA; t += BLK) locStage[t] = 0;
        ms_zero(C, tid);
        __syncthreads();
        #pragma unroll
        for (int i = 0; i < ITEMS_A; i++)
            if (f[i] >= 0) atomicAdd(&C.hist[f[i] >> SEGBITS], 1);
        __syncthreads();
        ms_scan_alloc(C, cntA + (size_t)bl * NSEG, tid);
        __syncthreads();
        #pragma unroll
        for (int i = 0; i < ITEMS_A; i++) {
            if (f[i] >= 0) {
                int j = jb + (i >> 2) * (BLK * 4) + tid * 4 + (i & 3);
                int s = f[i] >> SEGBITS;
                int r = atomicAdd(&C.cursor[s], 1);
                int pos = C.lstart[s] + r;
                staged[pos] = ((f[i] & (SEG - 1)) << JBITS) | j;
                stagedSeg[pos] = (unsigned char)s;
            }
        }
        __syncthreads();
        ms_copy_lds(C, staged, stagedSeg, bktA + (size_t)bl * PSTRIDE_A, CAPA,
                    locStage, jb, tid);
        __syncthreads();
        int* lrow = locA + (size_t)bl * N;
        #pragma unroll
        for (int q = 0; q < ITEMS_A / 4; q++) {
            int j0 = jb + q * (BLK * 4) + tid * 4;
            int o = q * (BLK * 4) + tid * 4;
            if (j0 + 3 < N) {
                iv4 v = { locStage[o], locStage[o + 1], locStage[o + 2], locStage[o + 3] };
                __builtin_nontemporal_store(v, (iv4*)(lrow + j0));
            } else {
                for (int e = 0; e < 4 && j0 + e < N; e++) lrow[j0 + e] = locStage[o + e];
            }
        }
    } else {
        // ---------------- binBp path (corr gather + c-seg multisplit) ------
        int jb = ci * CHUNKB;
        const int* row = idx0 + (size_t)b * N;
        const int* crow = corr + (size_t)b * FCOUNT;
        int j0 = jb + tid * 4;
        int f4[4];
        if (j0 + 3 < N) {
            iv4 v = __builtin_nontemporal_load((const iv4*)(row + j0));
            f4[0] = v[0]; f4[1] = v[1]; f4[2] = v[2]; f4[3] = v[3];
        } else {
            #pragma unroll
            for (int s = 0; s < 4; s++) f4[s] = (j0 + s < N) ? row[j0 + s] : -1;
        }
        int cc[ITEMS_B];
        #pragma unroll
        for (int t = 0; t < ITEMS_B; t++) {     // unconditional NT gathers
            int ix = f4[t] < 0 ? 0 : f4[t];
            cc[t] = __builtin_nontemporal_load(crow + ix);
        }
        #pragma unroll
        for (int t = 0; t < ITEMS_B; t++)
            if (f4[t] < 0) cc[t] = -2;          // past-N pad
        for (int t = tid; t < CHUNKB; t += BLK) locStage[t] = -1;
        ms_zero(C, tid);
        __syncthreads();
        #pragma unroll
        for (int t = 0; t < ITEMS_B; t++)
            if (cc[t] >= 0) atomicAdd(&C.hist[cc[t] >> SEGBITS], 1);
        __syncthreads();
        ms_scan_alloc(C, cntB + (size_t)bl * NSEG, tid);
        __syncthreads();
        #pragma unroll
        for (int t = 0; t < ITEMS_B; t++) {
            if (cc[t] >= 0) {
                int s = cc[t] >> SEGBITS;
                int r = atomicAdd(&C.cursor[s], 1);
                int pos = C.lstart[s] + r;
                staged[pos] = ((cc[t] & (SEG - 1)) << JBITS) | (j0 + t);
                stagedSeg[pos] = (unsigned char)s;
            }
        }
        __syncthreads();
        ms_copy_lds(C, staged, stagedSeg, bktB + (size_t)bl * PSTRIDE_B, CAPB,
                    locStage, jb, tid);
        __syncthreads();
        int* lrow = locB + (size_t)bl * N;
        int o = tid * 4, jw = jb + o;
        if (jw + 3 < N) {
            iv4 v = { locStage[o], locStage[o + 1], locStage[o + 2], locStage[o + 3] };
            __builtin_nontemporal_store(v, (iv4*)(lrow + jw));
        } else {
            for (int e = 0; e < 4 && jw + e < N; e++) lrow[jw + e] = locStage[o + e];
        }
    }
}

// ---------------------------------------------------------------------------
// passC: per (pair, c-seg of 8192): build posv (inverse of idx1) then maxq
// (max j with c(j)=f) in ONE 32 KB LDS array (entries stashed in registers);
// overwrite bucket entries in place with result values:
//   A entry (f,g) -> (posv[f]==g) ? maxq[f] : -1   (= gt_matches1[g])
//   B entry (c,j) -> posv[c]                       (= gt_matches0[j])
__global__ __launch_bounds__(BLK) void passC_kernel(
        const int* __restrict__ cntA, int* __restrict__ bucketA,
        const int* __restrict__ cntB, int* __restrict__ bucketB) {
    __shared__ int arr[SEG];    // 32 KB: posv, then maxq
    int id = blockIdx.x, xcd = id & 7, k = id >> 3;
    int bl = xcd + 8 * (k / NSEG), s = k % NSEG;
    int tid = threadIdx.x;
    for (int t = tid; t < SEG; t += BLK) arr[t] = -1;
    __syncthreads();
    int nA = cntA[bl * NSEG + s]; if (nA > CAPA) nA = CAPA;
    int nB = cntB[bl * NSEG + s]; if (nB > CAPB) nB = CAPB;
    int* bA = bucketA + (size_t)bl * PSTRIDE_A + s * CAPA;
    int* bB = bucketB + (size_t)bl * PSTRIDE_B + s * CAPB;
    int eA[EPT_A], eB[EPT_B], r0[EPT_B];
    #pragma unroll
    for (int t = 0; t < EPT_A; t++) {
        int i = tid + t * BLK;
        eA[t] = 0;
        if (i < nA) {
            int e = bA[i];
            eA[t] = e;
            atomicMax(&arr[e >> JBITS], e & JMASK);
        }
    }
    __syncthreads();
    #pragma unroll
    for (int t = 0; t < EPT_B; t++) {
        int i = tid + t * BLK;
        eB[t] = 0; r0[t] = -1;
        if (i < nB) {
            int e = bB[i];
            eB[t] = e;
            r0[t] = arr[e >> JBITS];
        }
    }
    #pragma unroll
    for (int t = 0; t < EPT_A; t++) {
        int i = tid + t * BLK;
        if (i < nA && arr[eA[t] >> JBITS] == (eA[t] & JMASK))
            eA[t] |= 0x80000000;    // winner of its facet
    }
    __syncthreads();
    for (int t = tid; t < SEG; t += BLK) arr[t] = -1;
    __syncthreads();
    #pragma unroll
    for (int t = 0; t < EPT_B; t++) {
        int i = tid + t * BLK;
        if (i < nB)
            atomicMax(&arr[eB[t] >> JBITS], eB[t] & JMASK);
    }
    __syncthreads();
    #pragma unroll
    for (int t = 0; t < EPT_A; t++) {
        int i = tid + t * BLK;
        if (i < nA)
            bA[i] = (eA[t] < 0) ? arr[(eA[t] >> JBITS) & (SEG - 1)] : -1;
    }
    #pragma unroll
    for (int t = 0; t < EPT_B; t++) {
        int i = tid + t * BLK;
        if (i < nB) bB[i] = r0[t];
    }
}

// ---------------------------------------------------------------------------
// passD: j-ordered final pass, 16 j's per thread in 4 q-strided groups of 4:
// every load/store instruction is 64 lanes x 16 B contiguous. 32 unconditional
// gathers pinned before consumers via sched_barrier.
__global__ __launch_bounds__(BLK) void passD_kernel(
        const int* __restrict__ locA, const int* __restrict__ locB,
        const int* __restrict__ bucketA, const int* __restrict__ bucketB,
        const float* __restrict__ scores, float* __restrict__ out,
        int N, int ndblk, int b0) {
    int id = blockIdx.x, xcd = id & 7, k = id >> 3;
    int bl = xcd + 8 * (k / ndblk), jc = k % ndblk;
    int b = b0 + bl;
    int jb = jc * (BLK * JPT);
    int tid = threadIdx.x;
    const int* lA = locA + (size_t)bl * N;
    const int* lB = locB + (size_t)bl * N;
    const int* bA = bucketA + (size_t)bl * PSTRIDE_A;
    const int* bB = bucketB + (size_t)bl * PSTRIDE_B;
    const float* sc = scores + (size_t)b * N;
    size_t ob = (size_t)b * 3 * N;
    iv4 av[JPT / 4], bv[JPT / 4];
    fv4 sv[JPT / 4];
    #pragma unroll
    for (int q = 0; q < JPT / 4; q++) {
        int j = jb + q * (BLK * 4) + tid * 4;
        if (j + 3 < N) {
            av[q] = __builtin_nontemporal_load((const iv4*)(lA + j));
            bv[q] = __builtin_nontemporal_load((const iv4*)(lB + j));
            sv[q] = __builtin_nontemporal_load((const fv4*)(sc + j));
        } else {
            #pragma unroll
            for (int e = 0; e < 4; e++) {
                int jj = j + e;
                av[q][e] = (jj < N) ? lA[jj] : 0;
                bv[q][e] = (jj < N) ? lB[jj] : -1;
                sv[q][e] = (jj < N) ? sc[jj] : 0.0f;
            }
        }
    }
    int va[JPT], vb[JPT];
    #pragma unroll
    for (int t = 0; t < JPT; t++) {
        int bi = bv[t >> 2][t & 3];
        vb[t] = bB[bi < 0 ? 0 : bi];            // unconditional gather
    }
    #pragma unroll
    for (int t = 0; t < JPT; t++)
        va[t] = bA[av[t >> 2][t & 3]];
    __builtin_amdgcn_sched_barrier(0);          // all 32 gathers issued first
    #pragma unroll
    for (int q = 0; q < JPT / 4; q++) {
        int j = jb + q * (BLK * 4) + tid * 4;
        fv4 o0, o1, o2;
        #pragma unroll
        for (int e = 0; e < 4; e++) {
            int t = q * 4 + e;
            int v = (bv[q][e] < 0) ? -1 : vb[t];
            o0[e] = (float)v;
            o1[e] = (float)va[t];
            o2[e] = (v >= 0) ? sv[q][e] : 0.0f;
        }
        if (j + 3 < N) {
            __builtin_nontemporal_store(o0, (fv4*)(out + ob + j));
            __builtin_nontemporal_store(o1, (fv4*)(out + ob + N + j));
            __builtin_nontemporal_store(o2, (fv4*)(out + ob + 2 * N + j));
        } else {
            for (int e = 0; e < 4 && j + e < N; e++) {
                out[ob + j + e] = o0[e];
                out[ob + N + j + e] = o1[e];
                out[ob + 2 * N + j + e] = o2[e];
            }
        }
    }
}

// ---------------------------------------------------------------------------
extern "C" void kernel_launch(void* const* d_in, const int* in_sizes, int n_in,
                              void* d_out, int out_size, void* d_ws, size_t ws_size,
                              hipStream_t stream) {
    const int*   corr   = (const int*)d_in[0];
    const int*   idx0   = (const int*)d_in[1];
    const int*   idx1   = (const int*)d_in[2];
    const float* scores = (const float*)d_in[3];
    float* out = (float*)d_out;

    const int B = in_sizes[0] / FCOUNT;   // 64 (multiple of 8)
    const int N = in_sizes[1] / B;        // 200000 (< 2^18, multiple of 4)

    size_t cntSz  = (size_t)(NSEG + NSEG) * sizeof(int);   // per pair (A + B)
    size_t bASz   = (size_t)PSTRIDE_A * sizeof(int);
    size_t bBSz   = (size_t)PSTRIDE_B * sizeof(int);
    size_t locSz  = (size_t)N * sizeof(int);
    size_t perPair = cntSz + bASz + bBSz + 2 * locSz;   // ~3.31 MB

    // balanced chunking: avoid a tiny under-occupied tail chunk
    int CBmax = (int)(ws_size / perPair);
    CBmax &= ~7;              // multiple of 8 for XCD pinning
    if (CBmax > B) CBmax = B;
    if (CBmax < 8) CBmax = 8;
    int nch = (B + CBmax - 1) / CBmax;
    int CB = ((B + nch - 1) / nch + 7) & ~7;
    while (CB * nch < B) CB += 8;
    if (CB > CBmax) CB = CBmax;

    char* p = (char*)d_ws;
    int* cntA = (int*)p; p += (size_t)CB * NSEG * sizeof(int);
    int* cntB = (int*)p; p += (size_t)CB * NSEG * sizeof(int);
    int* bktA = (int*)p; p += bASz * CB;
    int* bktB = (int*)p; p += bBSz * CB;
    int* locA = (int*)p; p += locSz * CB;
    int* locB = (int*)p;

    int nchunkB = (N + CHUNKB - 1) / CHUNKB;
    int nchunkA = (N + CHUNKA - 1) / CHUNKA;
    int per     = nchunkB + nchunkA;
    int ndblk   = (N + BLK * JPT - 1) / (BLK * JPT);

    for (int b0 = 0; b0 < B; b0 += CB) {
        int nb = B - b0; if (nb > CB) nb = CB;   // multiple of 8
        hipMemsetAsync(cntA, 0, (size_t)2 * CB * NSEG * sizeof(int), stream);
        bin_fused_kernel<<<nb * per, BLK, 0, stream>>>(
            corr, idx0, idx1, cntA, cntB, bktA, bktB, locA, locB,
            N, nchunkB, nchunkA, b0);
        passC_kernel<<<nb * NSEG, BLK, 0, stream>>>(cntA, bktA, cntB, bktB);
        passD_kernel<<<nb * ndblk, BLK, 0, stream>>>(locA, locB, bktA, bktB,
                                                     scores, out, N, ndblk, b0);
    }
}

// Round 18
// 312.517 us; speedup vs baseline: 1.3640x; 1.3640x over previous
//
#include <hip/hip_runtime.h>

#define FCOUNT 786432   // 12 * 256 * 256
#define SEGBITS 13
#define SEG 8192        // facets per segment (passC LDS geometry)
#define NSEG 96         // FCOUNT / SEG
#define JBITS 18
#define JMASK ((1 << JBITS) - 1)
#define BLK 256
#define ITEMS_A 8
#define CHUNKA (BLK * ITEMS_A)  // 2048 items per A-chunk
#define ITEMS_B 4
#define CHUNKB (BLK * ITEMS_B)  // 1024 items per B-chunk (proven r12/r15 geometry)
#define JPT 16                  // j's per thread in passD (4 q-groups of 4)
#define CAPA 2400       // idx1-seg bucket cap (mean 2083, sigma 45)
#define CAPB 2048       // c-seg bucket cap (mean ~1667, sigma 41)
#define EPT_A 10        // ceil(CAPA / BLK)
#define EPT_B 8         // CAPB / BLK
#define PSTRIDE_A (NSEG * CAPA)
#define PSTRIDE_B (NSEG * CAPB)

typedef int   iv4 __attribute__((ext_vector_type(4)));
typedef float fv4 __attribute__((ext_vector_type(4)));

template <int NS> struct MsCtl {
    int hist[NS], lstart[NS], gbase[NS], cursor[NS], wsum[BLK / 64];
    int total;
};

template <int NS>
__device__ __forceinline__ void ms_zero(MsCtl<NS>& C, int tid) {
    if (tid < NS) { C.hist[tid] = 0; C.cursor[tid] = 0; }
}

// hist complete: exclusive scan -> lstart, global bucket alloc -> gbase, total
template <int NS>
__device__ __forceinline__ void ms_scan_alloc(MsCtl<NS>& C, int* __restrict__ cntRow,
                                              int tid) {
    int v = (tid < NS) ? C.hist[tid] : 0;
    int lane = tid & 63, w = tid >> 6;
    #pragma unroll
    for (int d = 1; d < 64; d <<= 1) {
        int u = __shfl_up(v, d, 64);
        if (lane >= d) v += u;
    }
    if (lane == 63) C.wsum[w] = v;
    __syncthreads();
    int add = 0;
    for (int ww = 0; ww < w; ww++) add += C.wsum[ww];
    v += add;
    if (tid < NS) {
        C.lstart[tid] = v - C.hist[tid];
        C.gbase[tid] = C.hist[tid] ? atomicAdd(&cntRow[tid], C.hist[tid]) : 0;
        if (tid == NS - 1) C.total = v;
    }
}

// DENSE staged copy; bucket writes CACHED (sub-line scatter runs merge in L2
// -- NT here caused 2.6x HBM write amplification, round 14 lesson; NT gather
// LOADS cost 3.2x FETCH, round 17 lesson: NT only for single-touch streams).
// loc lands in the block's LDS window (flushed coalesced NT later).
template <int NS>
__device__ __forceinline__ void ms_copy_lds(const MsCtl<NS>& C,
                                            const int* __restrict__ staged,
                                            const unsigned char* __restrict__ stagedSeg,
                                            int* __restrict__ bktPair, int cap,
                                            int* __restrict__ locStage, int jb,
                                            int tid) {
    int total = C.total;
    for (int i = tid; i < total; i += BLK) {
        int s = stagedSeg[i];
        int d = C.gbase[s] + (i - C.lstart[s]);
        if (d < cap) {
            int e = staged[i];
            int slot = s * cap + d;
            bktPair[slot] = e;
            locStage[(e & JMASK) - jb] = slot;
        }
    }
}

// ---------------------------------------------------------------------------
// Fused binning kernel (round-15 proven structure). Per pair: nchunkB B-chunks
// (corr gather + c-seg multisplit) and nchunkA A-chunks (idx1 f-seg
// multisplit), interleaved 2:1 so gather-latency blocks co-schedule with
// compute blocks. All loc writes staged in LDS, flushed as coalesced NT int4.
__global__ __launch_bounds__(BLK) void bin_fused_kernel(
        const int* __restrict__ corr, const int* __restrict__ idx0,
        const int* __restrict__ idx1, int* __restrict__ cntA,
        int* __restrict__ cntB, int* __restrict__ bktA, int* __restrict__ bktB,
        int* __restrict__ locA, int* __restrict__ locB,
        int N, int nchunkB, int nchunkA, int b0) {
    __shared__ MsCtl<NSEG> C;
    __shared__ int staged[CHUNKA];              // B path uses first CHUNKB
    __shared__ unsigned char stagedSeg[CHUNKA];
    __shared__ int locStage[CHUNKA];
    int id = blockIdx.x, xcd = id & 7, k = id >> 3;   // XCD-pin pair
    int per = nchunkB + nchunkA;
    int bl = xcd + 8 * (k / per), m = k % per;
    int b = b0 + bl, tid = threadIdx.x;
    bool isA; int ci;
    if (nchunkB == 2 * nchunkA) {               // interleave B,B,A,B,B,A,...
        isA = (m % 3 == 2);
        ci = isA ? m / 3 : m - (m + 1) / 3;
    } else {
        isA = (m >= nchunkB);
        ci = isA ? m - nchunkB : m;
    }

    if (isA) {
        // ---------------- binA path (idx1 multisplit) ----------------
        int jb = ci * CHUNKA;
        const int* row = idx1 + (size_t)b * N;
        int f[ITEMS_A];
        #pragma unroll
        for (int q = 0; q < ITEMS_A / 4; q++) {
            int j0 = jb + q * (BLK * 4) + tid * 4;
            if (j0 + 3 < N) {
                iv4 v = __builtin_nontemporal_load((const iv4*)(row + j0));
                f[q * 4 + 0] = v[0]; f[q * 4 + 1] = v[1];
                f[q * 4 + 2] = v[2]; f[q * 4 + 3] = v[3];
            } else {
                #pragma unroll
                for (int s = 0; s < 4; s++)
                    f[q * 4 + s] = (j0 + s < N) ? row[j0 + s] : -1;
            }
        }
        for (int t = tid; t < CHUNKA; t += BLK) locStage[t] = 0;
        ms_zero(C, tid);
        __syncthreads();
        #pragma unroll
        for (int i = 0; i < ITEMS_A; i++)
            if (f[i] >= 0) atomicAdd(&C.hist[f[i] >> SEGBITS], 1);
        __syncthreads();
        ms_scan_alloc(C, cntA + (size_t)bl * NSEG, tid);
        __syncthreads();
        #pragma unroll
        for (int i = 0; i < ITEMS_A; i++) {
            if (f[i] >= 0) {
                int j = jb + (i >> 2) * (BLK * 4) + tid * 4 + (i & 3);
                int s = f[i] >> SEGBITS;
                int r = atomicAdd(&C.cursor[s], 1);
                int pos = C.lstart[s] + r;
                staged[pos] = ((f[i] & (SEG - 1)) << JBITS) | j;
                stagedSeg[pos] = (unsigned char)s;
            }
        }
        __syncthreads();
        ms_copy_lds(C, staged, stagedSeg, bktA + (size_t)bl * PSTRIDE_A, CAPA,
                    locStage, jb, tid);
        __syncthreads();
        int* lrow = locA + (size_t)bl * N;
        #pragma unroll
        for (int q = 0; q < ITEMS_A / 4; q++) {
            int j0 = jb + q * (BLK * 4) + tid * 4;
            int o = q * (BLK * 4) + tid * 4;
            if (j0 + 3 < N) {
                iv4 v = { locStage[o], locStage[o + 1], locStage[o + 2], locStage[o + 3] };
                __builtin_nontemporal_store(v, (iv4*)(lrow + j0));
            } else {
                for (int e = 0; e < 4 && j0 + e < N; e++) lrow[j0 + e] = locStage[o + e];
            }
        }
    } else {
        // ---------------- binBp path (corr gather + c-seg multisplit) ------
        int jb = ci * CHUNKB;
        const int* row = idx0 + (size_t)b * N;
        const int* crow = corr + (size_t)b * FCOUNT;
        int j0 = jb + tid * 4;
        int f4[4];
        if (j0 + 3 < N) {
            iv4 v = __builtin_nontemporal_load((const iv4*)(row + j0));
            f4[0] = v[0]; f4[1] = v[1]; f4[2] = v[2]; f4[3] = v[3];
        } else {
            #pragma unroll
            for (int s = 0; s < 4; s++) f4[s] = (j0 + s < N) ? row[j0 + s] : -1;
        }
        int cc[ITEMS_B];
        #pragma unroll
        for (int t = 0; t < ITEMS_B; t++) {     // unconditional: 4 in flight
            int ix = f4[t] < 0 ? 0 : f4[t];
            cc[t] = crow[ix];
        }
        #pragma unroll
        for (int t = 0; t < ITEMS_B; t++)
            if (f4[t] < 0) cc[t] = -2;          // past-N pad
        for (int t = tid; t < CHUNKB; t += BLK) locStage[t] = -1;
        ms_zero(C, tid);
        __syncthreads();
        #pragma unroll
        for (int t = 0; t < ITEMS_B; t++)
            if (cc[t] >= 0) atomicAdd(&C.hist[cc[t] >> SEGBITS], 1);
        __syncthreads();
        ms_scan_alloc(C, cntB + (size_t)bl * NSEG, tid);
        __syncthreads();
        #pragma unroll
        for (int t = 0; t < ITEMS_B; t++) {
            if (cc[t] >= 0) {
                int s = cc[t] >> SEGBITS;
                int r = atomicAdd(&C.cursor[s], 1);
                int pos = C.lstart[s] + r;
                staged[pos] = ((cc[t] & (SEG - 1)) << JBITS) | (j0 + t);
                stagedSeg[pos] = (unsigned char)s;
            }
        }
        __syncthreads();
        ms_copy_lds(C, staged, stagedSeg, bktB + (size_t)bl * PSTRIDE_B, CAPB,
                    locStage, jb, tid);
        __syncthreads();
        int* lrow = locB + (size_t)bl * N;
        int o = tid * 4, jw = jb + o;
        if (jw + 3 < N) {
            iv4 v = { locStage[o], locStage[o + 1], locStage[o + 2], locStage[o + 3] };
            __builtin_nontemporal_store(v, (iv4*)(lrow + jw));
        } else {
            for (int e = 0; e < 4 && jw + e < N; e++) lrow[jw + e] = locStage[o + e];
        }
    }
}

// ---------------------------------------------------------------------------
// passC: per (pair, c-seg of 8192): build posv (inverse of idx1) then maxq
// (max j with c(j)=f) in ONE 32 KB LDS array (entries stashed in registers);
// overwrite bucket entries in place with result values:
//   A entry (f,g) -> (posv[f]==g) ? maxq[f] : -1   (= gt_matches1[g])
//   B entry (c,j) -> posv[c]                       (= gt_matches0[j])
__global__ __launch_bounds__(BLK) void passC_kernel(
        const int* __restrict__ cntA, int* __restrict__ bucketA,
        const int* __restrict__ cntB, int* __restrict__ bucketB) {
    __shared__ int arr[SEG];    // 32 KB: posv, then maxq
    int id = blockIdx.x, xcd = id & 7, k = id >> 3;
    int bl = xcd + 8 * (k / NSEG), s = k % NSEG;
    int tid = threadIdx.x;
    for (int t = tid; t < SEG; t += BLK) arr[t] = -1;
    __syncthreads();
    int nA = cntA[bl * NSEG + s]; if (nA > CAPA) nA = CAPA;
    int nB = cntB[bl * NSEG + s]; if (nB > CAPB) nB = CAPB;
    int* bA = bucketA + (size_t)bl * PSTRIDE_A + s * CAPA;
    int* bB = bucketB + (size_t)bl * PSTRIDE_B + s * CAPB;
    int eA[EPT_A], eB[EPT_B], r0[EPT_B];
    #pragma unroll
    for (int t = 0; t < EPT_A; t++) {
        int i = tid + t * BLK;
        eA[t] = 0;
        if (i < nA) {
            int e = bA[i];
            eA[t] = e;
            atomicMax(&arr[e >> JBITS], e & JMASK);
        }
    }
    __syncthreads();
    #pragma unroll
    for (int t = 0; t < EPT_B; t++) {
        int i = tid + t * BLK;
        eB[t] = 0; r0[t] = -1;
        if (i < nB) {
            int e = bB[i];
            eB[t] = e;
            r0[t] = arr[e >> JBITS];
        }
    }
    #pragma unroll
    for (int t = 0; t < EPT_A; t++) {
        int i = tid + t * BLK;
        if (i < nA && arr[eA[t] >> JBITS] == (eA[t] & JMASK))
            eA[t] |= 0x80000000;    // winner of its facet
    }
    __syncthreads();
    for (int t = tid; t < SEG; t += BLK) arr[t] = -1;
    __syncthreads();
    #pragma unroll
    for (int t = 0; t < EPT_B; t++) {
        int i = tid + t * BLK;
        if (i < nB)
            atomicMax(&arr[eB[t] >> JBITS], eB[t] & JMASK);
    }
    __syncthreads();
    #pragma unroll
    for (int t = 0; t < EPT_A; t++) {
        int i = tid + t * BLK;
        if (i < nA)
            bA[i] = (eA[t] < 0) ? arr[(eA[t] >> JBITS) & (SEG - 1)] : -1;
    }
    #pragma unroll
    for (int t = 0; t < EPT_B; t++) {
        int i = tid + t * BLK;
        if (i < nB) bB[i] = r0[t];
    }
}

// ---------------------------------------------------------------------------
// passD: j-ordered final pass, 16 j's per thread in 4 q-strided groups of 4:
// every load/store instruction is 64 lanes x 16 B contiguous. 32 unconditional
// gathers pinned before consumers via sched_barrier.
__global__ __launch_bounds__(BLK) void passD_kernel(
        const int* __restrict__ locA, const int* __restrict__ locB,
        const int* __restrict__ bucketA, const int* __restrict__ bucketB,
        const float* __restrict__ scores, float* __restrict__ out,
        int N, int ndblk, int b0) {
    int id = blockIdx.x, xcd = id & 7, k = id >> 3;
    int bl = xcd + 8 * (k / ndblk), jc = k % ndblk;
    int b = b0 + bl;
    int jb = jc * (BLK * JPT);
    int tid = threadIdx.x;
    const int* lA = locA + (size_t)bl * N;
    const int* lB = locB + (size_t)bl * N;
    const int* bA = bucketA + (size_t)bl * PSTRIDE_A;
    const int* bB = bucketB + (size_t)bl * PSTRIDE_B;
    const float* sc = scores + (size_t)b * N;
    size_t ob = (size_t)b * 3 * N;
    iv4 av[JPT / 4], bv[JPT / 4];
    fv4 sv[JPT / 4];
    #pragma unroll
    for (int q = 0; q < JPT / 4; q++) {
        int j = jb + q * (BLK * 4) + tid * 4;
        if (j + 3 < N) {
            av[q] = __builtin_nontemporal_load((const iv4*)(lA + j));
            bv[q] = __builtin_nontemporal_load((const iv4*)(lB + j));
            sv[q] = __builtin_nontemporal_load((const fv4*)(sc + j));
        } else {
            #pragma unroll
            for (int e = 0; e < 4; e++) {
                int jj = j + e;
                av[q][e] = (jj < N) ? lA[jj] : 0;
                bv[q][e] = (jj < N) ? lB[jj] : -1;
                sv[q][e] = (jj < N) ? sc[jj] : 0.0f;
            }
        }
    }
    int va[JPT], vb[JPT];
    #pragma unroll
    for (int t = 0; t < JPT; t++) {
        int bi = bv[t >> 2][t & 3];
        vb[t] = bB[bi < 0 ? 0 : bi];            // unconditional gather
    }
    #pragma unroll
    for (int t = 0; t < JPT; t++)
        va[t] = bA[av[t >> 2][t & 3]];
    __builtin_amdgcn_sched_barrier(0);          // all 32 gathers issued first
    #pragma unroll
    for (int q = 0; q < JPT / 4; q++) {
        int j = jb + q * (BLK * 4) + tid * 4;
        fv4 o0, o1, o2;
        #pragma unroll
        for (int e = 0; e < 4; e++) {
            int t = q * 4 + e;
            int v = (bv[q][e] < 0) ? -1 : vb[t];
            o0[e] = (float)v;
            o1[e] = (float)va[t];
            o2[e] = (v >= 0) ? sv[q][e] : 0.0f;
        }
        if (j + 3 < N) {
            __builtin_nontemporal_store(o0, (fv4*)(out + ob + j));
            __builtin_nontemporal_store(o1, (fv4*)(out + ob + N + j));
            __builtin_nontemporal_store(o2, (fv4*)(out + ob + 2 * N + j));
        } else {
            for (int e = 0; e < 4 && j + e < N; e++) {
                out[ob + j + e] = o0[e];
                out[ob + N + j + e] = o1[e];
                out[ob + 2 * N + j + e] = o2[e];
            }
        }
    }
}

// ---------------------------------------------------------------------------
extern "C" void kernel_launch(void* const* d_in, const int* in_sizes, int n_in,
                              void* d_out, int out_size, void* d_ws, size_t ws_size,
                              hipStream_t stream) {
    const int*   corr   = (const int*)d_in[0];
    const int*   idx0   = (const int*)d_in[1];
    const int*   idx1   = (const int*)d_in[2];
    const float* scores = (const float*)d_in[3];
    float* out = (float*)d_out;

    const int B = in_sizes[0] / FCOUNT;   // 64 (multiple of 8)
    const int N = in_sizes[1] / B;        // 200000 (< 2^18, multiple of 4)

    size_t cntSz  = (size_t)(NSEG + NSEG) * sizeof(int);   // per pair (A + B)
    size_t bASz   = (size_t)PSTRIDE_A * sizeof(int);
    size_t bBSz   = (size_t)PSTRIDE_B * sizeof(int);
    size_t locSz  = (size_t)N * sizeof(int);
    size_t perPair = cntSz + bASz + bBSz + 2 * locSz;   // ~3.31 MB

    // balanced chunking: avoid a tiny under-occupied tail chunk
    int CBmax = (int)(ws_size / perPair);
    CBmax &= ~7;              // multiple of 8 for XCD pinning
    if (CBmax > B) CBmax = B;
    if (CBmax < 8) CBmax = 8;
    int nch = (B + CBmax - 1) / CBmax;
    int CB = ((B + nch - 1) / nch + 7) & ~7;
    while (CB * nch < B) CB += 8;
    if (CB > CBmax) CB = CBmax;

    char* p = (char*)d_ws;
    int* cntA = (int*)p; p += (size_t)CB * NSEG * sizeof(int);
    int* cntB = (int*)p; p += (size_t)CB * NSEG * sizeof(int);
    int* bktA = (int*)p; p += bASz * CB;
    int* bktB = (int*)p; p += bBSz * CB;
    int* locA = (int*)p; p += locSz * CB;
    int* locB = (int*)p;

    int nchunkB = (N + CHUNKB - 1) / CHUNKB;
    int nchunkA = (N + CHUNKA - 1) / CHUNKA;
    int per     = nchunkB + nchunkA;
    int ndblk   = (N + BLK * JPT - 1) / (BLK * JPT);

    for (int b0 = 0; b0 < B; b0 += CB) {
        int nb = B - b0; if (nb > CB) nb = CB;   // multiple of 8
        hipMemsetAsync(cntA, 0, (size_t)2 * CB * NSEG * sizeof(int), stream);
        bin_fused_kernel<<<nb * per, BLK, 0, stream>>>(
            corr, idx0, idx1, cntA, cntB, bktA, bktB, locA, locB,
            N, nchunkB, nchunkA, b0);
        passC_kernel<<<nb * NSEG, BLK, 0, stream>>>(cntA, bktA, cntB, bktB);
        passD_kernel<<<nb * ndblk, BLK, 0, stream>>>(locA, locB, bktA, bktB,
                                                     scores, out, N, ndblk, b0);
    }
}